// Round 9
// baseline (1132.824 us; speedup 1.0000x reference)
//
#include <hip/hip_runtime.h>

#define T_STEPS 512
#define D_IN    32
#define H       64
#define NB      4     // batch elements per block

// ---- DPP cross-lane add over aligned 8-lane groups (chunk id = lane&7) ----
template<int CTRL>
__device__ __forceinline__ float dpp_add(float v) {
    int m = __builtin_amdgcn_update_dpp(0, __float_as_int(v), CTRL, 0xf, 0xf, true);
    return v + __int_as_float(m);
}
__device__ __forceinline__ float red8(float v) {
    v = dpp_add<0xB1>(v);   // quad_perm [1,0,3,2] : + lane^1
    v = dpp_add<0x4E>(v);   // quad_perm [2,3,0,1] : + lane^2
    v = dpp_add<0x141>(v);  // row_half_mirror    : + mirrored lane in 8-group
    return v;
}

__device__ __forceinline__ float sigf(float x) {
    return 1.0f / (1.0f + __expf(-x));
}
__device__ __forceinline__ float tanhf_(float x) {
    float e = __expf(2.0f * x);
    return 1.0f - 2.0f / (e + 1.0f);
}

__global__ __launch_bounds__(1024, 4)
void lstm2_fused(const float* __restrict__ x,
                 const float* __restrict__ Wih0, const float* __restrict__ Whh0,
                 const float* __restrict__ bih0, const float* __restrict__ bhh0,
                 const float* __restrict__ Wih1, const float* __restrict__ Whh1,
                 const float* __restrict__ bih1, const float* __restrict__ bhh1,
                 const float* __restrict__ Wfc,  const float* __restrict__ bfc,
                 float* __restrict__ out)
{
    // Double-buffered (parity) state; ONE barrier per step.
    // vin[p][b] = { x_t (32), h0 (64) }: chunk c (12 floats) reads float4 at
    //   12c+4q -> bank starts {0,12,24,4,16,28,8,20}+4q : perfect 32-bank tile.
    __shared__ __align__(16) float vin[2][NB][96];
    // u1[p][b][c][20]: chunk c holds k in [16c,16c+16), +4 pad.
    //   float4 at [c][4q] -> starts {0,20,8,28,16,4,24,12}+4q : perfect tile.
    __shared__ __align__(16) float u1[2][NB][8][20];

    const int tid  = threadIdx.x;
    const int b0   = blockIdx.x * NB;
    // waves 0-7 = L0 (512 thr), waves 8-15 = L1 (512 thr): 2 L0 + 2 L1 per SIMD
    const bool isL0 = tid < 512;
    const int tl   = isL0 ? tid : tid - 512;
    const int c    = tl & 7;        // K-chunk id; chunks c<4 also own batch c's cell
    const int rg   = tl >> 3;       // state index j in [0,64)

    // ---- per-thread weights: 4 gate-rows {g*64+rg} x 1 chunk, ONE array.
    //      L0: q0..2 (12-float chunk of K=96) = 48 floats; L1: q0..3 = 64 floats.
    //      Rules: single array <=64 floats (R2-proven at 1024 thr), no pointers
    //      into locals, constant indices, acc declared+consumed in-branch. ----
    float4 wq[4][4];
    if (isL0) {
#pragma unroll
        for (int q = 0; q < 3; ++q)
#pragma unroll
            for (int g = 0; g < 4; ++g) {
                int r = g * 64 + rg;
                float tv[4];
#pragma unroll
                for (int e = 0; e < 4; ++e) {
                    int k = 12 * c + 4 * q + e;
                    tv[e] = (k < 32) ? Wih0[r * D_IN + k] : Whh0[r * H + (k - 32)];
                }
                wq[q][g] = make_float4(tv[0], tv[1], tv[2], tv[3]);
            }
#pragma unroll
        for (int g = 0; g < 4; ++g) wq[3][g] = make_float4(0.f, 0.f, 0.f, 0.f);
    } else {
#pragma unroll
        for (int q = 0; q < 4; ++q)
#pragma unroll
            for (int g = 0; g < 4; ++g) {
                int r = g * 64 + rg;
                float tv[4];
#pragma unroll
                for (int e = 0; e < 4; ++e) {
                    int k = 16 * c + 4 * q + e;
                    tv[e] = (k < 64) ? Wih1[r * H + k] : Whh1[r * H + (k - 64)];
                }
                wq[q][g] = make_float4(tv[0], tv[1], tv[2], tv[3]);
            }
    }

    // biases + cell state: thread (c<4, rg) owns cell (state rg, batch c)
    const bool cellown = (c < 4);
    float bi = 0.f, bf_ = 0.f, bg_ = 0.f, bo = 0.f, cst = 0.f;
    if (isL0 && cellown) {
        bi  = bih0[rg]       + bhh0[rg];
        bf_ = bih0[64 + rg]  + bhh0[64 + rg];
        bg_ = bih0[128 + rg] + bhh0[128 + rg];
        bo  = bih0[192 + rg] + bhh0[192 + rg];
    } else if (!isL0 && cellown) {
        bi  = bih1[rg]       + bhh1[rg];
        bf_ = bih1[64 + rg]  + bhh1[64 + rg];
        bg_ = bih1[128 + rg] + bhh1[128 + rg];
        bo  = bih1[192 + rg] + bhh1[192 + rg];
    }

    // x-prefetch owners: threads 896..1023 cover (4 b x 32 k) of one timestep
    const bool isx = tid >= 896;
    int xb = 0, xk = 0;
    const float* xp = nullptr;
    if (isx) {
        int idx = tid - 896;
        xb = idx >> 5; xk = idx & 31;
        xp = x + (size_t)(b0 + xb) * T_STEPS * D_IN + xk;
    }

    // ---- init: zero u1 (both parities), h-part of vin[0]; stage x_0 ----
    for (int i = tid; i < 2 * NB * 8 * 20; i += 1024) ((float*)u1)[i] = 0.f;
    if (tid < 256) vin[0][tid >> 6][32 + (tid & 63)] = 0.f;
    if (isx) vin[0][xb][xk] = xp[0];
    __syncthreads();

    for (int it = 0; it <= T_STEPS; ++it) {
        const int p = it & 1;

        float xpre = 0.f;
        const bool havex = isx && (it + 1 < T_STEPS);
        if (havex) xpre = xp[(size_t)(it + 1) * D_IN];

        if (isL0) {
            if (it < T_STEPS) {
                float acc[4][NB];
#pragma unroll
                for (int g = 0; g < 4; ++g)
#pragma unroll
                    for (int b = 0; b < NB; ++b) acc[g][b] = 0.f;
#pragma unroll
                for (int q = 0; q < 3; ++q) {
                    float4 v0 = *(const float4*)&vin[p][0][12 * c + 4 * q];
                    float4 v1 = *(const float4*)&vin[p][1][12 * c + 4 * q];
                    float4 v2 = *(const float4*)&vin[p][2][12 * c + 4 * q];
                    float4 v3 = *(const float4*)&vin[p][3][12 * c + 4 * q];
#pragma unroll
                    for (int g = 0; g < 4; ++g) {
                        float4 w = wq[q][g];
                        acc[g][0] = fmaf(w.x, v0.x, acc[g][0]);
                        acc[g][0] = fmaf(w.y, v0.y, acc[g][0]);
                        acc[g][0] = fmaf(w.z, v0.z, acc[g][0]);
                        acc[g][0] = fmaf(w.w, v0.w, acc[g][0]);
                        acc[g][1] = fmaf(w.x, v1.x, acc[g][1]);
                        acc[g][1] = fmaf(w.y, v1.y, acc[g][1]);
                        acc[g][1] = fmaf(w.z, v1.z, acc[g][1]);
                        acc[g][1] = fmaf(w.w, v1.w, acc[g][1]);
                        acc[g][2] = fmaf(w.x, v2.x, acc[g][2]);
                        acc[g][2] = fmaf(w.y, v2.y, acc[g][2]);
                        acc[g][2] = fmaf(w.z, v2.z, acc[g][2]);
                        acc[g][2] = fmaf(w.w, v2.w, acc[g][2]);
                        acc[g][3] = fmaf(w.x, v3.x, acc[g][3]);
                        acc[g][3] = fmaf(w.y, v3.y, acc[g][3]);
                        acc[g][3] = fmaf(w.z, v3.z, acc[g][3]);
                        acc[g][3] = fmaf(w.w, v3.w, acc[g][3]);
                    }
                }
#pragma unroll
                for (int g = 0; g < 4; ++g)
#pragma unroll
                    for (int b = 0; b < NB; ++b) acc[g][b] = red8(acc[g][b]);
                if (cellown) {
                    float gi = (c == 1) ? acc[0][1] : acc[0][0];
                    gi       = (c == 2) ? acc[0][2] : gi;
                    gi       = (c == 3) ? acc[0][3] : gi;
                    float gf = (c == 1) ? acc[1][1] : acc[1][0];
                    gf       = (c == 2) ? acc[1][2] : gf;
                    gf       = (c == 3) ? acc[1][3] : gf;
                    float gg = (c == 1) ? acc[2][1] : acc[2][0];
                    gg       = (c == 2) ? acc[2][2] : gg;
                    gg       = (c == 3) ? acc[2][3] : gg;
                    float go = (c == 1) ? acc[3][1] : acc[3][0];
                    go       = (c == 2) ? acc[3][2] : go;
                    go       = (c == 3) ? acc[3][3] : go;
                    gi += bi; gf += bf_; gg += bg_; go += bo;
                    float cc = sigf(gf) * cst + sigf(gi) * tanhf_(gg);
                    cst = cc;
                    float hh = sigf(go) * tanhf_(cc);
                    vin[p ^ 1][c][32 + rg]            = hh;  // L0 next input
                    u1[p ^ 1][c][rg >> 4][rg & 15]    = hh;  // L1 input k=rg
                }
            }
        } else {
            if (it >= 1) {
                float acc[4][NB];
#pragma unroll
                for (int g = 0; g < 4; ++g)
#pragma unroll
                    for (int b = 0; b < NB; ++b) acc[g][b] = 0.f;
#pragma unroll
                for (int q = 0; q < 4; ++q) {
                    float4 v0 = *(const float4*)&u1[p][0][c][4 * q];
                    float4 v1 = *(const float4*)&u1[p][1][c][4 * q];
                    float4 v2 = *(const float4*)&u1[p][2][c][4 * q];
                    float4 v3 = *(const float4*)&u1[p][3][c][4 * q];
#pragma unroll
                    for (int g = 0; g < 4; ++g) {
                        float4 w = wq[q][g];
                        acc[g][0] = fmaf(w.x, v0.x, acc[g][0]);
                        acc[g][0] = fmaf(w.y, v0.y, acc[g][0]);
                        acc[g][0] = fmaf(w.z, v0.z, acc[g][0]);
                        acc[g][0] = fmaf(w.w, v0.w, acc[g][0]);
                        acc[g][1] = fmaf(w.x, v1.x, acc[g][1]);
                        acc[g][1] = fmaf(w.y, v1.y, acc[g][1]);
                        acc[g][1] = fmaf(w.z, v1.z, acc[g][1]);
                        acc[g][1] = fmaf(w.w, v1.w, acc[g][1]);
                        acc[g][2] = fmaf(w.x, v2.x, acc[g][2]);
                        acc[g][2] = fmaf(w.y, v2.y, acc[g][2]);
                        acc[g][2] = fmaf(w.z, v2.z, acc[g][2]);
                        acc[g][2] = fmaf(w.w, v2.w, acc[g][2]);
                        acc[g][3] = fmaf(w.x, v3.x, acc[g][3]);
                        acc[g][3] = fmaf(w.y, v3.y, acc[g][3]);
                        acc[g][3] = fmaf(w.z, v3.z, acc[g][3]);
                        acc[g][3] = fmaf(w.w, v3.w, acc[g][3]);
                    }
                }
#pragma unroll
                for (int g = 0; g < 4; ++g)
#pragma unroll
                    for (int b = 0; b < NB; ++b) acc[g][b] = red8(acc[g][b]);
                if (cellown) {
                    float gi = (c == 1) ? acc[0][1] : acc[0][0];
                    gi       = (c == 2) ? acc[0][2] : gi;
                    gi       = (c == 3) ? acc[0][3] : gi;
                    float gf = (c == 1) ? acc[1][1] : acc[1][0];
                    gf       = (c == 2) ? acc[1][2] : gf;
                    gf       = (c == 3) ? acc[1][3] : gf;
                    float gg = (c == 1) ? acc[2][1] : acc[2][0];
                    gg       = (c == 2) ? acc[2][2] : gg;
                    gg       = (c == 3) ? acc[2][3] : gg;
                    float go = (c == 1) ? acc[3][1] : acc[3][0];
                    go       = (c == 2) ? acc[3][2] : go;
                    go       = (c == 3) ? acc[3][3] : go;
                    gi += bi; gf += bf_; gg += bg_; go += bo;
                    float cc = sigf(gf) * cst + sigf(gi) * tanhf_(gg);
                    cst = cc;
                    float hh = sigf(go) * tanhf_(cc);
                    u1[p ^ 1][c][4 + (rg >> 4)][rg & 15] = hh;  // k = 64+rg
                }
            }
        }
        if (havex) vin[p ^ 1][xb][xk] = xpre;
        __syncthreads();   // the ONE barrier per step
    }

    // ---- final FC on h1[T-1] (last L1 update at it=512, p=0 -> wrote u1[1]) ----
    if (tid < NB) {
        float s = bfc[0];
#pragma unroll
        for (int k = 0; k < H; ++k)
            s += u1[1][tid][4 + (k >> 4)][k & 15] * Wfc[k];
        out[b0 + tid] = s;
    }
}

extern "C" void kernel_launch(void* const* d_in, const int* in_sizes, int n_in,
                              void* d_out, int out_size, void* d_ws, size_t ws_size,
                              hipStream_t stream) {
    const float* x    = (const float*)d_in[0];
    const float* Wih0 = (const float*)d_in[1];
    const float* Whh0 = (const float*)d_in[2];
    const float* bih0 = (const float*)d_in[3];
    const float* bhh0 = (const float*)d_in[4];
    const float* Wih1 = (const float*)d_in[5];
    const float* Whh1 = (const float*)d_in[6];
    const float* bih1 = (const float*)d_in[7];
    const float* bhh1 = (const float*)d_in[8];
    const float* Wfc  = (const float*)d_in[9];
    const float* bfc  = (const float*)d_in[10];
    float* out = (float*)d_out;

    const int B = out_size;            // 1024
    dim3 grid(B / NB), block(1024);
    hipLaunchKernelGGL(lstm2_fused, grid, block, 0, stream,
                       x, Wih0, Whh0, bih0, bhh0,
                       Wih1, Whh1, bih1, bhh1, Wfc, bfc, out);
}

// Round 10
// 930.172 us; speedup vs baseline: 1.2179x; 1.2179x over previous
//
#include <hip/hip_runtime.h>

#define T_STEPS 512

typedef __attribute__((ext_vector_type(8))) short s16x8;  // 8 bf16 (4 VGPRs)
typedef __attribute__((ext_vector_type(4))) float f32x4;  // MFMA C/D

__device__ __forceinline__ short f2bf(float v) {          // fp32 -> bf16 RNE
    unsigned u = __float_as_uint(v);
    return (short)((u + 0x7FFFu + ((u >> 16) & 1u)) >> 16);
}
__device__ __forceinline__ float bf2f(short b) {
    return __uint_as_float(((unsigned)(unsigned short)b) << 16);
}
__device__ __forceinline__ float sigf(float x)  { return 1.f / (1.f + __expf(-x)); }
__device__ __forceinline__ float tanhf_(float x){ float e = __expf(2.f * x); return 1.f - 2.f / (e + 1.f); }

// Each block: 4 batches, 1024 threads = 16 waves. Wave w owns states 4w..4w+3
// of BOTH layers. Weight rows are permuted per wave: tile row m = s*4 + g, so
// D (col=lane&15, row=(lane>>4)*4+reg) gives lane (q4, n<4) all 4 gates of
// (state 4w+q4, batch n) in its 4 acc regs -> in-lane cell, 1 barrier/step.
__global__ __launch_bounds__(1024, 4)
void lstm2_mfma(const float* __restrict__ x,
                const float* __restrict__ Wih0, const float* __restrict__ Whh0,
                const float* __restrict__ bih0, const float* __restrict__ bhh0,
                const float* __restrict__ Wih1, const float* __restrict__ Whh1,
                const float* __restrict__ bih1, const float* __restrict__ bhh1,
                const float* __restrict__ Wfc,  const float* __restrict__ bfc,
                float* __restrict__ out)
{
    // B-operand buffers, bf16, [parity][n(16)][k]. Strides 104/136 shorts ->
    // b128 quad index (13n+..)/(17n+..) mod 32: 2-way worst case (free).
    __shared__ __align__(16) short vinB[2][16][104];  // k: 0..31 x_t, 32..95 h0
    __shared__ __align__(16) short u1B [2][16][136];  // k: 0..63 h0, 64..127 h1

    const int tid  = threadIdx.x;
    const int w    = tid >> 6;       // wave 0..15
    const int lane = tid & 63;
    const int n16  = lane & 15;      // MFMA col (batch for n<4) / A-row m
    const int q4   = lane >> 4;      // quad: D-state-slot; A k-run
    const int b0   = blockIdx.x * 4;

    // ---- A fragments (weights, bf16, loop-invariant). A[m=lane&15][k=q4*8+j].
    //      tile row m -> gate m&3, local state m>>2 -> global row: ----
    const int rowW = (n16 & 3) * 64 + 4 * w + (n16 >> 2);
    s16x8 a0, a1, a2;        // L0: K=96  = 3 tiles {x, h0_lo, h0_hi}
    s16x8 e0, e1, e2, e3;    // L1: K=128 = 4 tiles {h0 x2, h1 x2}
#pragma unroll
    for (int j = 0; j < 8; ++j) {
        a0[j] = f2bf(Wih0[rowW * 32 + q4 * 8 + j]);
        a1[j] = f2bf(Whh0[rowW * 64 + q4 * 8 + j]);
        a2[j] = f2bf(Whh0[rowW * 64 + 32 + q4 * 8 + j]);
        e0[j] = f2bf(Wih1[rowW * 64 + q4 * 8 + j]);
        e1[j] = f2bf(Wih1[rowW * 64 + 32 + q4 * 8 + j]);
        e2[j] = f2bf(Whh1[rowW * 64 + q4 * 8 + j]);
        e3[j] = f2bf(Whh1[rowW * 64 + 32 + q4 * 8 + j]);
    }

    // ---- bias as the MFMA C seed: reg p = gate p of state jL, all cols ----
    const int jL = 4 * w + q4;       // global state 0..63 owned in D by this lane
    f32x4 bias0, bias1;
#pragma unroll
    for (int p_ = 0; p_ < 4; ++p_) {
        bias0[p_] = bih0[p_ * 64 + jL] + bhh0[p_ * 64 + jL];
        bias1[p_] = bih1[p_ * 64 + jL] + bhh1[p_ * 64 + jL];
    }

    // ---- x stagers: waves 0..3, lanes with 4<=n16<12 (disjoint from cell lanes).
    //      wave w stages batch w's 32 x values. ----
    const bool isx = (w < 4) && (n16 >= 4) && (n16 < 12);
    const int  xk  = q4 * 8 + (n16 - 4);                 // 0..31
    const float* xp = x + ((size_t)(b0 + w) * T_STEPS) * 32 + xk;

    // ---- init: zero both buffers (n>=4 cols stay zero forever); stage x_0 ----
    for (int i = tid; i < 2 * 16 * 104 / 2; i += 1024) ((int*)vinB)[i] = 0;
    for (int i = tid; i < 2 * 16 * 136 / 2; i += 1024) ((int*)u1B)[i]  = 0;
    __syncthreads();
    if (isx) vinB[0][w][xk] = f2bf(xp[0]);
    __syncthreads();

    float cst0 = 0.f, cst1 = 0.f;    // fp32 cell states (precision anchor)

    for (int it = 0; it <= T_STEPS; ++it) {
        const int p = it & 1;

        float xpre = 0.f;
        const bool havex = isx && (it + 1 < T_STEPS);
        if (havex) xpre = xp[(size_t)(it + 1) * 32];

        // ---- B fragments: lane reads B[k=q4*8+j][n=n16] ----
        const short* vb = &vinB[p][n16][q4 * 8];
        s16x8 vb0 = *(const s16x8*)(vb);
        s16x8 vb1 = *(const s16x8*)(vb + 32);
        s16x8 vb2 = *(const s16x8*)(vb + 64);
        const short* ub = &u1B[p][n16][q4 * 8];
        s16x8 ub0 = *(const s16x8*)(ub);
        s16x8 ub1 = *(const s16x8*)(ub + 32);
        s16x8 ub2 = *(const s16x8*)(ub + 64);
        s16x8 ub3 = *(const s16x8*)(ub + 96);

        // ---- gates via MFMA (bias pre-seeded in C) ----
        f32x4 d0 = __builtin_amdgcn_mfma_f32_16x16x32_bf16(a0, vb0, bias0, 0, 0, 0);
        d0 = __builtin_amdgcn_mfma_f32_16x16x32_bf16(a1, vb1, d0, 0, 0, 0);
        d0 = __builtin_amdgcn_mfma_f32_16x16x32_bf16(a2, vb2, d0, 0, 0, 0);
        f32x4 d1 = __builtin_amdgcn_mfma_f32_16x16x32_bf16(e0, ub0, bias1, 0, 0, 0);
        d1 = __builtin_amdgcn_mfma_f32_16x16x32_bf16(e1, ub1, d1, 0, 0, 0);
        d1 = __builtin_amdgcn_mfma_f32_16x16x32_bf16(e2, ub2, d1, 0, 0, 0);
        d1 = __builtin_amdgcn_mfma_f32_16x16x32_bf16(e3, ub3, d1, 0, 0, 0);

        // ---- in-lane cells: lane (q4, n16<4) owns (state jL, batch n16) ----
        if (n16 < 4) {
            if (it < T_STEPS) {            // L0 at step `it`
                float cc = sigf(d0[1]) * cst0 + sigf(d0[0]) * tanhf_(d0[2]);
                cst0 = cc;
                short hb = f2bf(sigf(d0[3]) * tanhf_(cc));
                vinB[p ^ 1][n16][32 + jL] = hb;   // L0's next input
                u1B [p ^ 1][n16][jL]      = hb;   // L1's input (k = jL)
            }
            if (it >= 1) {                 // L1 at step `it-1`
                float cc = sigf(d1[1]) * cst1 + sigf(d1[0]) * tanhf_(d1[2]);
                cst1 = cc;
                u1B[p ^ 1][n16][64 + jL] = f2bf(sigf(d1[3]) * tanhf_(cc));
            }
        }
        if (havex) vinB[p ^ 1][w][xk] = f2bf(xpre);
        __syncthreads();                   // the ONE barrier per step
    }

    // ---- final FC on h1[T-1] (last L1 write: it=512, p=0 -> u1B[1]) ----
    if (tid < 4) {
        float s = bfc[0];
#pragma unroll
        for (int k = 0; k < 64; ++k)
            s += bf2f(u1B[1][tid][64 + k]) * Wfc[k];
        out[b0 + tid] = s;
    }
}

extern "C" void kernel_launch(void* const* d_in, const int* in_sizes, int n_in,
                              void* d_out, int out_size, void* d_ws, size_t ws_size,
                              hipStream_t stream) {
    const float* x    = (const float*)d_in[0];
    const float* Wih0 = (const float*)d_in[1];
    const float* Whh0 = (const float*)d_in[2];
    const float* bih0 = (const float*)d_in[3];
    const float* bhh0 = (const float*)d_in[4];
    const float* Wih1 = (const float*)d_in[5];
    const float* Whh1 = (const float*)d_in[6];
    const float* bih1 = (const float*)d_in[7];
    const float* bhh1 = (const float*)d_in[8];
    const float* Wfc  = (const float*)d_in[9];
    const float* bfc  = (const float*)d_in[10];
    float* out = (float*)d_out;

    const int B = out_size;            // 1024
    dim3 grid(B / 4), block(1024);
    hipLaunchKernelGGL(lstm2_mfma, grid, block, 0, stream,
                       x, Wih0, Whh0, bih0, bhh0,
                       Wih1, Whh1, bih1, bhh1, Wfc, bfc, out);
}